// Round 11
// baseline (289.896 us; speedup 1.0000x reference)
//
#include <hip/hip_runtime.h>
#include <hip/hip_bf16.h>

#define NB 32
#define NPOS 4096
#define NSLOT 8
#define HIDD 256
#define DDIM 256
#define SCALE_F 0.0625f
#define EPS_F 1e-8f
#define NCHUNK 32
#define CPOS 128
#define TPOS 32

typedef __attribute__((ext_vector_type(4))) float f32x4;
typedef __attribute__((ext_vector_type(8))) short s16x8;
typedef __attribute__((ext_vector_type(2))) unsigned int u32x2;
typedef _Float16 h16x2 __attribute__((ext_vector_type(2)));

__device__ __forceinline__ unsigned short f2bf(float f) {
    unsigned int x = __float_as_uint(f);
    x = (x + 0x7fffu + ((x >> 16) & 1u)) >> 16;
    return (unsigned short)x;
}
__device__ __forceinline__ unsigned short f2h(float f) {
    _Float16 h = (_Float16)f;
    return __builtin_bit_cast(unsigned short, h);
}
__device__ __forceinline__ unsigned pack2h(float a, float b) {
    return (unsigned)f2h(a) | ((unsigned)f2h(b) << 16);
}
__device__ __forceinline__ h16x2 u2h(unsigned u) { return __builtin_bit_cast(h16x2, u); }
__device__ __forceinline__ h16x2 mkh(float a0, float a1) {
    h16x2 r; r[0] = (_Float16)a0; r[1] = (_Float16)a1; return r;
}
__device__ __forceinline__ void dot4(f32x4& acc, uint4 wv, h16x2 av) {
    acc[0] = __builtin_amdgcn_fdot2(av, u2h(wv.x), acc[0], false);
    acc[1] = __builtin_amdgcn_fdot2(av, u2h(wv.y), acc[1], false);
    acc[2] = __builtin_amdgcn_fdot2(av, u2h(wv.z), acc[2], false);
    acc[3] = __builtin_amdgcn_fdot2(av, u2h(wv.w), acc[3], false);
}
__device__ __forceinline__ float blkred(float v, float* red4) {
    #pragma unroll
    for (int m = 32; m; m >>= 1) v += __shfl_xor(v, m);
    int w = threadIdx.x >> 6;
    if ((threadIdx.x & 63) == 0) red4[w] = v;
    __syncthreads();
    float s = red4[0] + red4[1] + red4[2] + red4[3];
    __syncthreads();
    return s;
}

// ---------------- LayerNorm(inputs) -> bf16 (NT input load) ----------------
__global__ __launch_bounds__(256) void k_ln_in(
        const float* __restrict__ x, const float* __restrict__ g,
        const float* __restrict__ b, unsigned short* __restrict__ lnx) {
    int lane = threadIdx.x & 63;
    int wave = threadIdx.x >> 6;
    long row = (long)blockIdx.x * 4 + wave;
    f32x4 v = __builtin_nontemporal_load((const f32x4*)(x + row * 256) + lane);
    float s = v[0] + v[1] + v[2] + v[3];
    float sq = v[0]*v[0] + v[1]*v[1] + v[2]*v[2] + v[3]*v[3];
    #pragma unroll
    for (int m = 32; m; m >>= 1) { s += __shfl_xor(s, m); sq += __shfl_xor(sq, m); }
    float mean = s * 0.00390625f;
    float rstd = rsqrtf(sq * 0.00390625f - mean * mean + 1e-5f);
    const float4 gg = ((const float4*)g)[lane];
    const float4 bb = ((const float4*)b)[lane];
    ushort4 o;
    o.x = f2bf((v[0] - mean) * rstd * gg.x + bb.x);
    o.y = f2bf((v[1] - mean) * rstd * gg.y + bb.y);
    o.z = f2bf((v[2] - mean) * rstd * gg.z + bb.z);
    o.w = f2bf((v[3] - mean) * rstd * gg.w + bb.w);
    ((ushort4*)(lnx + row * 256))[lane] = o;
}

__device__ __forceinline__ unsigned packrowh(const float* __restrict__ W, int hp, int N, int c) {
    return pack2h(W[(2*hp)*N + c], W[(2*hp+1)*N + c]);
}

// ---- k_prep: 0..383 pack Whh/W1/W2; 384..511 M1=Wq@WkT (+v1,w2,sc2);
//              512..543 M_ih=Wv@Wih; 544 bih' = bv@Wih + bih ----
__global__ __launch_bounds__(256) void k_prep(
        const float* __restrict__ Wq, const float* __restrict__ Wk,
        const float* __restrict__ bq, const float* __restrict__ bk,
        const float* __restrict__ Wv, const float* __restrict__ Wih,
        const float* __restrict__ Whh, const float* __restrict__ W1,
        const float* __restrict__ W2, const float* __restrict__ bih,
        const float* __restrict__ bv,
        unsigned* __restrict__ WhhP, unsigned* __restrict__ W1P,
        unsigned* __restrict__ W2P, unsigned* __restrict__ M1P,
        unsigned* __restrict__ M_ihP, float* __restrict__ bihP,
        float* __restrict__ v1, float* __restrict__ w2, float* __restrict__ sc2) {
    int t = threadIdx.x;
    if (blockIdx.x < 384) {
        int i = blockIdx.x * 256 + t;
        if (i < 65536) {
            int hp1 = i >> 9, c1 = i & 511;
            W1P[i] = packrowh(W1, hp1, 512, c1);
            int hp2 = i >> 8, c2 = i & 255;
            W2P[i] = packrowh(W2, hp2, 256, c2);
        }
        if (i < 98304) {
            int hp = i / 768, c = i % 768;
            WhhP[i] = packrowh(Whh, hp, 768, c);
        }
        return;
    }
    if (blockIdx.x < 512) {
        __shared__ float wq0[256], wq1[256], bqL[256];
        __shared__ float red4[4];
        int e2 = blockIdx.x - 384;
        wq0[t] = Wq[(2*e2)*256 + t];
        wq1[t] = Wq[(2*e2+1)*256 + t];
        bqL[t] = bq[t];
        __syncthreads();
        const float4* wkr = (const float4*)(Wk + (long)t * 256);
        float a0 = 0.f, a1 = 0.f;
        for (int d = 0; d < 64; d++) {
            float4 k4 = wkr[d];
            a0 += wq0[4*d]*k4.x + wq0[4*d+1]*k4.y + wq0[4*d+2]*k4.z + wq0[4*d+3]*k4.w;
            a1 += wq1[4*d]*k4.x + wq1[4*d+1]*k4.y + wq1[4*d+2]*k4.z + wq1[4*d+3]*k4.w;
        }
        M1P[e2*256 + t] = pack2h(a0, a1);
        float p0 = blkred(wq0[t] * bk[t], red4);
        float p1 = blkred(wq1[t] * bk[t], red4);
        if (t == 0) { w2[2*e2] = p0; w2[2*e2+1] = p1; }
        if (e2 == 0) {
            float av = 0.f;
            for (int d = 0; d < 64; d++) {
                float4 k4 = wkr[d];
                av += bqL[4*d]*k4.x + bqL[4*d+1]*k4.y + bqL[4*d+2]*k4.z + bqL[4*d+3]*k4.w;
            }
            v1[t] = av;
            float p2 = blkred(bqL[t] * bk[t], red4);
            if (t == 0) sc2[0] = p2;
        }
        return;
    }
    if (blockIdx.x < 544) {
        __shared__ float wvr[8][256];
        int bb = blockIdx.x - 512;
        #pragma unroll
        for (int r = 0; r < 8; r++) wvr[r][t] = Wv[(8*bb + r)*256 + t];
        __syncthreads();
        for (int jj = 0; jj < 3; jj++) {
            int j = t + jj*256;
            float acc[8] = {0.f,0.f,0.f,0.f,0.f,0.f,0.f,0.f};
            for (int c = 0; c < 256; c++) {
                float w = Wih[c*768 + j];
                #pragma unroll
                for (int r = 0; r < 8; r++) acc[r] += wvr[r][c] * w;
            }
            #pragma unroll
            for (int p = 0; p < 4; p++)
                M_ihP[(4*bb + p)*768 + j] = pack2h(acc[2*p], acc[2*p+1]);
        }
        return;
    }
    // bih' = bv@Wih + bih
    for (int jj = 0; jj < 3; jj++) {
        int j = t + jj*256;
        float a = bih[j];
        for (int c = 0; c < 256; c++) a += bv[c] * Wih[c*768 + j];
        bihP[j] = a;
    }
}

// ---- qk_tail (iter-0 only, fp32 weights) ----
__device__ __forceinline__ void qk_tail(
        float v0, float v1_, int b, int s0,
        const float* __restrict__ lng, const float* __restrict__ lnb,
        const float* __restrict__ Wq, const float* __restrict__ bq,
        const float* __restrict__ Wk, const float* __restrict__ bk,
        unsigned short* __restrict__ qkg, float* __restrict__ qbkg,
        float (*sh)[256], float (*red)[4]) {
    int c = threadIdx.x;
    float s_0 = v0, q_0 = v0 * v0, s_1 = v1_, q_1 = v1_ * v1_;
    #pragma unroll
    for (int m = 32; m; m >>= 1) {
        s_0 += __shfl_xor(s_0, m); q_0 += __shfl_xor(q_0, m);
        s_1 += __shfl_xor(s_1, m); q_1 += __shfl_xor(q_1, m);
    }
    if ((c & 63) == 0) { int w = c >> 6; red[w][0]=s_0; red[w][1]=q_0; red[w][2]=s_1; red[w][3]=q_1; }
    __syncthreads();
    float S0 = red[0][0]+red[1][0]+red[2][0]+red[3][0];
    float Q0 = red[0][1]+red[1][1]+red[2][1]+red[3][1];
    float S1 = red[0][2]+red[1][2]+red[2][2]+red[3][2];
    float Q1 = red[0][3]+red[1][3]+red[2][3]+red[3][3];
    float m0 = S0 * 0.00390625f, r0 = rsqrtf(Q0 * 0.00390625f - m0*m0 + 1e-5f);
    float m1 = S1 * 0.00390625f, r1 = rsqrtf(Q1 * 0.00390625f - m1*m1 + 1e-5f);
    float gc = lng[c], bc = lnb[c];
    sh[0][c] = (v0 - m0) * r0 * gc + bc;
    sh[1][c] = (v1_ - m1) * r1 * gc + bc;
    __syncthreads();
    float qa0 = bq[c], qa1 = qa0;
    for (int h = 0; h < 256; h += 4) {
        float w0 = Wq[(h+0)*256+c], w1 = Wq[(h+1)*256+c];
        float w2_ = Wq[(h+2)*256+c], w3 = Wq[(h+3)*256+c];
        float4 x0 = *(const float4*)&sh[0][h], x1 = *(const float4*)&sh[1][h];
        qa0 += x0.x*w0 + x0.y*w1 + x0.z*w2_ + x0.w*w3;
        qa1 += x1.x*w0 + x1.y*w1 + x1.z*w2_ + x1.w*w3;
    }
    __syncthreads();
    sh[0][c] = qa0; sh[1][c] = qa1;
    float bkc = bk[c];
    float p0 = qa0 * bkc, p1 = qa1 * bkc;
    #pragma unroll
    for (int m = 32; m; m >>= 1) { p0 += __shfl_xor(p0, m); p1 += __shfl_xor(p1, m); }
    __syncthreads();
    if ((c & 63) == 0) { int w = c >> 6; red[w][0] = p0; red[w][1] = p1; }
    __syncthreads();
    if (c < 2) qbkg[b*8 + s0 + c] = SCALE_F * (red[0][c]+red[1][c]+red[2][c]+red[3][c]);
    float k0 = 0.f, k1 = 0.f;
    const float* wkr = Wk + (long)c * 256;
    for (int d = 0; d < 256; d += 4) {
        float4 wk4 = *(const float4*)&wkr[d];
        float4 x0 = *(const float4*)&sh[0][d], x1 = *(const float4*)&sh[1][d];
        k0 += x0.x*wk4.x + x0.y*wk4.y + x0.z*wk4.z + x0.w*wk4.w;
        k1 += x1.x*wk4.x + x1.y*wk4.y + x1.z*wk4.z + x1.w*wk4.w;
    }
    qkg[(b*8 + s0    )*256 + c] = f2bf(SCALE_F * k0);
    qkg[(b*8 + s0 + 1)*256 + c] = f2bf(SCALE_F * k1);
}

__global__ __launch_bounds__(256) void k_init(
        const float* __restrict__ noise, const float* __restrict__ mu,
        const float* __restrict__ sig, const float* __restrict__ lng,
        const float* __restrict__ lnb, const float* __restrict__ Wq,
        const float* __restrict__ bq, const float* __restrict__ Wk,
        const float* __restrict__ bk, float* __restrict__ slots,
        unsigned short* __restrict__ qkg, float* __restrict__ qbkg) {
    __shared__ float sh[2][256];
    __shared__ float red[4][4];
    int b = blockIdx.x >> 2, rp = blockIdx.x & 3;
    int s0 = rp * 2, r0 = b * 8 + s0;
    int c = threadIdx.x;
    float v0 = mu[c] + sig[c] * noise[r0*256 + c];
    float v1 = mu[c] + sig[c] * noise[(r0+1)*256 + c];
    slots[r0*256 + c] = v0;
    slots[(r0+1)*256 + c] = v1;
    qk_tail(v0, v1, b, s0, lng, lnb, Wq, bq, Wk, bk, qkg, qbkg, sh, red);
}

// ------- streaming attention (R7 version, proven) -------
__global__ __launch_bounds__(128) void k_stream(
        const unsigned short* __restrict__ lnx, const unsigned short* __restrict__ qk,
        const float* __restrict__ qbk, float* __restrict__ Upart,
        float* __restrict__ dpart) {
    __shared__ unsigned short xt[TPOS * 256];
    __shared__ float Ured[8 * 256];
    __shared__ float dred[8];
    int b = blockIdx.x >> 5, ch = blockIdx.x & 31;
    int t = threadIdx.x;
    int l = t & 63, w = t >> 6;
    for (int i = t; i < 2048; i += 128) Ured[i] = 0.f;
    if (t < 8) dred[t] = 0.f;
    int slot = l & 15, g = l >> 4;
    s16x8 qkf[8];
    float qbkv = 0.f;
    if (slot < 8) {
        const unsigned short* qrow = qk + (b*8 + slot) * 256;
        #pragma unroll
        for (int hk = 0; hk < 8; hk++)
            qkf[hk] = *(const s16x8*)(qrow + hk*32 + 8*g);
        qbkv = qbk[b*8 + slot];
    } else {
        #pragma unroll
        for (int hk = 0; hk < 8; hk++) qkf[hk] = (s16x8)0;
    }
    f32x4 uacc[16];
    #pragma unroll
    for (int i = 0; i < 16; i++) uacc[i] = (f32x4)0.f;
    float dreg = 0.f;
    int gbase = (b * NPOS + ch * CPOS) * 256;
    int pw = w * 16;
    __syncthreads();
    for (int tile = 0; tile < 4; tile++) {
        #pragma unroll
        for (int i = 0; i < 8; i++) {
            int c = t + 128 * i;
            int p = c >> 5, hc = c & 31;
            int4 v = *(const int4*)(lnx + gbase + (tile*TPOS + p)*256 + hc*8);
            *(int4*)&xt[p*256 + ((hc ^ (p & 15)) << 3)] = v;
        }
        __syncthreads();
        f32x4 acc = (f32x4)0.f;
        {
            int prow = pw + (l & 15);
            const unsigned short* xrow = &xt[prow * 256];
            int sw = prow & 15;
            #pragma unroll
            for (int hk = 0; hk < 8; hk++) {
                s16x8 a = *(const s16x8*)(xrow + (((hk*4 + g) ^ sw) << 3));
                acc = __builtin_amdgcn_mfma_f32_16x16x32_bf16(a, qkf[hk], acc, 0, 0, 0);
            }
        }
        float at[4];
        #pragma unroll
        for (int r = 0; r < 4; r++) {
            float v = acc[r] + qbkv;
            float m = v;
            m = fmaxf(m, __shfl_xor(m, 1));
            m = fmaxf(m, __shfl_xor(m, 2));
            m = fmaxf(m, __shfl_xor(m, 4));
            float e = __expf(v - m);
            float sum = e;
            sum += __shfl_xor(sum, 1);
            sum += __shfl_xor(sum, 2);
            sum += __shfl_xor(sum, 4);
            float a = e / sum;
            at[r] = a;
            dreg += a;
        }
        u32x2 a2;
        a2.x = (unsigned)f2bf(at[0]) | ((unsigned)f2bf(at[1]) << 16);
        a2.y = (unsigned)f2bf(at[2]) | ((unsigned)f2bf(at[3]) << 16);
        int p0 = pw + 4 * g;
        int hl = l & 7;
        #pragma unroll
        for (int hc = 0; hc < 16; hc++) {
            int hcol = hc * 2 + ((l & 15) >> 3);
            unsigned e0 = xt[(p0+0)*256 + ((hcol ^ ((p0+0) & 15)) << 3) + hl];
            unsigned e1 = xt[(p0+1)*256 + ((hcol ^ ((p0+1) & 15)) << 3) + hl];
            unsigned e2 = xt[(p0+2)*256 + ((hcol ^ ((p0+2) & 15)) << 3) + hl];
            unsigned e3 = xt[(p0+3)*256 + ((hcol ^ ((p0+3) & 15)) << 3) + hl];
            u32x2 b2;
            b2.x = e0 | (e1 << 16);
            b2.y = e2 | (e3 << 16);
            asm volatile("v_mfma_f32_16x16x16_bf16 %0, %1, %2, %0"
                         : "+v"(uacc[hc]) : "v"(a2), "v"(b2));
        }
        __syncthreads();
    }
    if (g < 2) {
        #pragma unroll
        for (int hc = 0; hc < 16; hc++) {
            int h = hc * 16 + (l & 15);
            #pragma unroll
            for (int r = 0; r < 4; r++)
                atomicAdd(&Ured[(4*g + r)*256 + h], uacc[hc][r]);
        }
    }
    dreg += __shfl_xor(dreg, 16);
    dreg += __shfl_xor(dreg, 32);
    if (slot < 8 && g == 0) atomicAdd(&dred[slot], dreg);
    __syncthreads();
    float* up = Upart + (long)(b * NCHUNK + ch) * 2048;
    for (int i = t; i < 2048; i += 128) up[i] = Ured[i];
    if (t < 8) dpart[(b * NCHUNK + ch) * 8 + t] = dred[t];
}

// ---- 1024-thread duplicated-column layernorm ----
__device__ __forceinline__ float ln1024(float v, int c, const float* __restrict__ g,
                                        const float* __restrict__ b, float (*red)[2]) {
    float s1 = v, s2 = v * v;
    #pragma unroll
    for (int m = 32; m; m >>= 1) { s1 += __shfl_xor(s1, m); s2 += __shfl_xor(s2, m); }
    int w = threadIdx.x >> 6;
    if ((threadIdx.x & 63) == 0) { red[w][0] = s1; red[w][1] = s2; }
    __syncthreads();
    float S = 0.f, Q = 0.f;
    #pragma unroll
    for (int i = 0; i < 16; i++) { S += red[i][0]; Q += red[i][1]; }
    float mean = S * (1.f/1024.f);
    float rstd = rsqrtf(Q * (1.f/1024.f) - mean*mean + 1e-5f);
    __syncthreads();
    return (v - mean) * rstd * g[c] + b[c];
}

// ---- k_post v8: 1 row/block, 1024 threads, fused M_ih/M1 weights ----
__global__ __launch_bounds__(1024) void k_post(
        const float* __restrict__ Upart, const float* __restrict__ dpart,
        const unsigned* __restrict__ M_ihP, const unsigned* __restrict__ WhhP,
        const float* __restrict__ bihP, const float* __restrict__ bhh,
        const float* __restrict__ lnmg, const float* __restrict__ lnmb,
        const unsigned* __restrict__ W1P, const float* __restrict__ b1,
        const unsigned* __restrict__ W2P, const float* __restrict__ b2,
        const float* __restrict__ lnsg, const float* __restrict__ lnsb,
        const unsigned* __restrict__ M1P, const float* __restrict__ v1g,
        const float* __restrict__ w2g, const float* __restrict__ sc2g,
        float* __restrict__ slots, unsigned short* __restrict__ qkg,
        float* __restrict__ qbkg, float* __restrict__ outp, int last) {
    __shared__ union {
        float PG[2][8][768];
        struct { float P16[16][256]; float H2[8][512]; } s;
    } sm;
    __shared__ float A[256], B[256], G2[2][768], H[512];
    __shared__ float red[16][2];
    __shared__ float scal[1];
    int r = blockIdx.x, b = r >> 3, s = r & 7;
    int t = threadIdx.x, c = t & 255, q = t >> 8;
    int cg = t & 63, kg16 = t >> 6;
    // Phase 1: U reduce + denom + slots
    {
        float u = 0.f;
        const float* ub = Upart + (long)b * NCHUNK * 2048 + s * 256 + c;
        #pragma unroll
        for (int i = 0; i < 8; i++) u += ub[(q * 8 + i) * 2048];
        sm.s.P16[q][c] = u;
        if (q == 1) B[c] = slots[r * 256 + c];
        if (t < 32) {
            float dv = dpart[(b * NCHUNK + t) * 8 + s];
            #pragma unroll
            for (int m = 16; m; m >>= 1) dv += __shfl_xor(dv, m);
            if (t == 0) scal[0] = dv;
        }
    }
    __syncthreads();
    float dn = 1.f / (scal[0] + (float)NPOS * EPS_F);
    if (q == 0)
        A[c] = (sm.s.P16[0][c] + sm.s.P16[1][c] + sm.s.P16[2][c] + sm.s.P16[3][c]) * dn;
    __syncthreads();
    // Phase 2: GRU partials (gi via M_ih on A=U/den; gh via Whh on B=slots)
    {
        int h = t >> 9;
        int kg = (t >> 6) & 7;
        const float* src = h ? B : A;
        const unsigned* W = h ? WhhP : M_ihP;
        f32x4 ar = (f32x4)0.f, az = (f32x4)0.f, an = (f32x4)0.f;
        #pragma unroll 4
        for (int i = 0; i < 16; i++) {
            int hp = kg * 16 + i;
            h16x2 av = mkh(src[2*hp], src[2*hp+1]);
            uint4 w0 = *(const uint4*)(W + hp*768 + 4*cg);
            uint4 w1 = *(const uint4*)(W + hp*768 + 256 + 4*cg);
            uint4 w2 = *(const uint4*)(W + hp*768 + 512 + 4*cg);
            dot4(ar, w0, av);
            dot4(az, w1, av);
            dot4(an, w2, av);
        }
        *(f32x4*)&sm.PG[h][kg][4*cg]       = ar;
        *(f32x4*)&sm.PG[h][kg][256 + 4*cg] = az;
        *(f32x4*)&sm.PG[h][kg][512 + 4*cg] = an;
    }
    __syncthreads();
    for (int idx = t; idx < 1536; idx += 1024) {
        int h = idx / 768, cc = idx - h * 768;
        float ss = 0.f;
        #pragma unroll
        for (int k = 0; k < 8; k++) ss += sm.PG[h][k][cc];
        G2[h][cc] = ss;
    }
    __syncthreads();
    // GRU elementwise (bih' folded constant)
    float spc = B[c];
    float gir = bihP[c]     + G2[0][c];
    float giz = bihP[c+256] + G2[0][c+256];
    float gin = bihP[c+512] + G2[0][c+512];
    float ghr = bhh[c]      + G2[1][c];
    float ghz = bhh[c+256]  + G2[1][c+256];
    float ghn = bhh[c+512]  + G2[1][c+512];
    float rg = 1.f/(1.f + __expf(-(gir+ghr)));
    float zg = 1.f/(1.f + __expf(-(giz+ghz)));
    float ng = tanhf(gin + rg*ghn);
    float hnew = (1.f - zg)*ng + zg*spc;
    float mmc = ln1024(hnew, c, lnmg, lnmb, red);
    if (q == 0) A[c] = mmc;
    __syncthreads();
    // MLP1
    {
        int kg = t >> 7, cg1 = t & 127;
        f32x4 acc = (f32x4)0.f;
        const uint4* wp = (const uint4*)(W1P + kg * 16 * 512 + 4 * cg1);
        #pragma unroll 4
        for (int i = 0; i < 16; i++) {
            uint4 wv = wp[i * 128];
            dot4(acc, wv, mkh(A[2*(kg*16+i)], A[2*(kg*16+i)+1]));
        }
        *(f32x4*)&sm.s.H2[kg][4*cg1] = acc;
    }
    __syncthreads();
    if (t < 512) {
        float ss = b1[t];
        #pragma unroll
        for (int k = 0; k < 8; k++) ss += sm.s.H2[k][t];
        H[t] = fmaxf(ss, 0.f);
    }
    __syncthreads();
    // MLP2 + residual
    {
        f32x4 acc = (f32x4)0.f;
        const uint4* wp = (const uint4*)(W2P + kg16 * 16 * 256 + 4 * cg);
        #pragma unroll 4
        for (int i = 0; i < 16; i++) {
            uint4 wv = wp[i * 64];
            dot4(acc, wv, mkh(H[2*(kg16*16+i)], H[2*(kg16*16+i)+1]));
        }
        *(f32x4*)&sm.s.P16[kg16][4*cg] = acc;
    }
    __syncthreads();
    float outc;
    {
        float ss = 0.f;
        #pragma unroll
        for (int k = 0; k < 16; k++) ss += sm.s.P16[k][c];
        outc = hnew + ss + b2[c];
    }
    if (t < 256) {
        slots[r*256 + c] = outc;
        if (last) outp[r*256 + c] = outc;
    }
    if (last) return;
    __syncthreads();
    // qk tail: LN -> qbk (w2/sc2) -> qk = sc@M1 + v1
    float sc = ln1024(outc, c, lnsg, lnsb, red);
    if (q == 0) A[c] = sc;
    {
        float v = sc * w2g[c];
        #pragma unroll
        for (int m = 32; m; m >>= 1) v += __shfl_xor(v, m);
        int w = t >> 6;
        if ((t & 63) == 0) red[w][0] = v;
    }
    __syncthreads();
    if (t == 0) {
        float S = 0.f;
        #pragma unroll
        for (int i = 0; i < 16; i++) S += red[i][0];
        qbkg[r] = SCALE_F * (0.25f * S + sc2g[0]);
    }
    {
        f32x4 acc = (f32x4)0.f;
        const uint4* wp = (const uint4*)(M1P + kg16 * 8 * 256 + 4 * cg);
        #pragma unroll
        for (int i = 0; i < 8; i++) {
            uint4 wv = wp[i * 64];
            dot4(acc, wv, mkh(A[2*(kg16*8+i)], A[2*(kg16*8+i)+1]));
        }
        *(f32x4*)&sm.s.P16[kg16][4*cg] = acc;
    }
    __syncthreads();
    if (t < 256) {
        float ss = 0.f;
        #pragma unroll
        for (int k = 0; k < 16; k++) ss += sm.s.P16[k][c];
        qkg[r*256 + c] = f2bf(SCALE_F * (ss + v1g[c]));
    }
}

extern "C" void kernel_launch(void* const* d_in, const int* in_sizes, int n_in,
                              void* d_out, int out_size, void* d_ws, size_t ws_size,
                              hipStream_t stream) {
    const float* inputs = (const float*)d_in[0];
    const float* noise  = (const float*)d_in[1];
    const float* mu     = (const float*)d_in[2];
    const float* sig    = (const float*)d_in[3];
    const float* lnig   = (const float*)d_in[4];
    const float* lnib   = (const float*)d_in[5];
    const float* lnsg   = (const float*)d_in[6];
    const float* lnsb   = (const float*)d_in[7];
    const float* lnmg   = (const float*)d_in[8];
    const float* lnmb   = (const float*)d_in[9];
    const float* Wq     = (const float*)d_in[10];
    const float* bq     = (const float*)d_in[11];
    const float* Wk     = (const float*)d_in[12];
    const float* bk     = (const float*)d_in[13];
    const float* Wv     = (const float*)d_in[14];
    const float* bv     = (const float*)d_in[15];
    const float* Wih    = (const float*)d_in[16];
    const float* Whh    = (const float*)d_in[17];
    const float* bih    = (const float*)d_in[18];
    const float* bhh    = (const float*)d_in[19];
    const float* W1     = (const float*)d_in[20];
    const float* b1     = (const float*)d_in[21];
    const float* W2     = (const float*)d_in[22];
    const float* b2     = (const float*)d_in[23];

    char* ws = (char*)d_ws;
    unsigned short* lnx = (unsigned short*)ws;
    size_t off = (size_t)NB * NPOS * HIDD * 2;                                   // 64 MB
    unsigned short* qkb = (unsigned short*)(ws + off); off += (size_t)NB*NSLOT*HIDD*2;
    float* qbk   = (float*)(ws + off); off += (size_t)NB*NSLOT*4;
    float* Upart = (float*)(ws + off); off += (size_t)NB*NCHUNK*NSLOT*HIDD*4;    // 8 MB
    float* dpart = (float*)(ws + off); off += (size_t)NB*NCHUNK*NSLOT*4;
    float* slots = (float*)(ws + off); off += (size_t)NB*NSLOT*DDIM*4;
    unsigned* WhhP  = (unsigned*)(ws + off); off += 98304u*4;
    unsigned* W1P   = (unsigned*)(ws + off); off += 65536u*4;
    unsigned* W2P   = (unsigned*)(ws + off); off += 65536u*4;
    unsigned* M1P   = (unsigned*)(ws + off); off += 32768u*4;
    unsigned* M_ihP = (unsigned*)(ws + off); off += 98304u*4;
    float* bihP = (float*)(ws + off); off += 768*4;
    float* v1   = (float*)(ws + off); off += 256*4;
    float* w2   = (float*)(ws + off); off += 256*4;
    float* sc2  = (float*)(ws + off); off += 64;

    k_prep<<<545, 256, 0, stream>>>(Wq, Wk, bq, bk, Wv, Wih, Whh, W1, W2, bih, bv,
                                    WhhP, W1P, W2P, M1P, M_ihP, bihP, v1, w2, sc2);
    k_ln_in<<<NB*NPOS/4, 256, 0, stream>>>(inputs, lnig, lnib, lnx);
    k_init<<<NB*4, 256, 0, stream>>>(noise, mu, sig, lnsg, lnsb, Wq, bq, Wk, bk,
                                     slots, qkb, qbk);
    for (int it = 0; it < 3; it++) {
        k_stream<<<NB*NCHUNK, 128, 0, stream>>>(lnx, qkb, qbk, Upart, dpart);
        k_post<<<NB*NSLOT, 1024, 0, stream>>>(Upart, dpart,
                                              M_ihP, WhhP, bihP, bhh,
                                              lnmg, lnmb, W1P, b1, W2P, b2,
                                              lnsg, lnsb, M1P, v1, w2, sc2,
                                              slots, qkb, qbk, (float*)d_out,
                                              it == 2 ? 1 : 0);
    }
}

// Round 12
// 261.328 us; speedup vs baseline: 1.1093x; 1.1093x over previous
//
#include <hip/hip_runtime.h>
#include <hip/hip_bf16.h>

#define NB 32
#define NPOS 4096
#define NSLOT 8
#define HIDD 256
#define DDIM 256
#define SCALE_F 0.0625f
#define EPS_F 1e-8f
#define NCHUNK 32
#define CPOS 128
#define TPOS 32

typedef __attribute__((ext_vector_type(4))) float f32x4;
typedef __attribute__((ext_vector_type(8))) short s16x8;
typedef __attribute__((ext_vector_type(2))) unsigned int u32x2;
typedef _Float16 h16x2 __attribute__((ext_vector_type(2)));

__device__ __forceinline__ unsigned short f2bf(float f) {
    unsigned int x = __float_as_uint(f);
    x = (x + 0x7fffu + ((x >> 16) & 1u)) >> 16;
    return (unsigned short)x;
}
__device__ __forceinline__ unsigned short f2h(float f) {
    _Float16 h = (_Float16)f;
    return __builtin_bit_cast(unsigned short, h);
}
__device__ __forceinline__ unsigned pack2h(float a, float b) {
    return (unsigned)f2h(a) | ((unsigned)f2h(b) << 16);
}
__device__ __forceinline__ h16x2 u2h(unsigned u) { return __builtin_bit_cast(h16x2, u); }
__device__ __forceinline__ h16x2 mkh(float a0, float a1) {
    h16x2 r; r[0] = (_Float16)a0; r[1] = (_Float16)a1; return r;
}
__device__ __forceinline__ void dot4(f32x4& acc, uint4 wv, h16x2 av) {
    acc[0] = __builtin_amdgcn_fdot2(av, u2h(wv.x), acc[0], false);
    acc[1] = __builtin_amdgcn_fdot2(av, u2h(wv.y), acc[1], false);
    acc[2] = __builtin_amdgcn_fdot2(av, u2h(wv.z), acc[2], false);
    acc[3] = __builtin_amdgcn_fdot2(av, u2h(wv.w), acc[3], false);
}
__device__ __forceinline__ float blkred(float v, float* red4) {
    #pragma unroll
    for (int m = 32; m; m >>= 1) v += __shfl_xor(v, m);
    int w = threadIdx.x >> 6;
    if ((threadIdx.x & 63) == 0) red4[w] = v;
    __syncthreads();
    float s = red4[0] + red4[1] + red4[2] + red4[3];
    __syncthreads();
    return s;
}

// ---------------- LayerNorm(inputs) -> bf16 (NT input load) ----------------
__global__ __launch_bounds__(256) void k_ln_in(
        const float* __restrict__ x, const float* __restrict__ g,
        const float* __restrict__ b, unsigned short* __restrict__ lnx) {
    int lane = threadIdx.x & 63;
    int wave = threadIdx.x >> 6;
    long row = (long)blockIdx.x * 4 + wave;
    f32x4 v = __builtin_nontemporal_load((const f32x4*)(x + row * 256) + lane);
    float s = v[0] + v[1] + v[2] + v[3];
    float sq = v[0]*v[0] + v[1]*v[1] + v[2]*v[2] + v[3]*v[3];
    #pragma unroll
    for (int m = 32; m; m >>= 1) { s += __shfl_xor(s, m); sq += __shfl_xor(sq, m); }
    float mean = s * 0.00390625f;
    float rstd = rsqrtf(sq * 0.00390625f - mean * mean + 1e-5f);
    const float4 gg = ((const float4*)g)[lane];
    const float4 bb = ((const float4*)b)[lane];
    ushort4 o;
    o.x = f2bf((v[0] - mean) * rstd * gg.x + bb.x);
    o.y = f2bf((v[1] - mean) * rstd * gg.y + bb.y);
    o.z = f2bf((v[2] - mean) * rstd * gg.z + bb.z);
    o.w = f2bf((v[3] - mean) * rstd * gg.w + bb.w);
    ((ushort4*)(lnx + row * 256))[lane] = o;
}

__device__ __forceinline__ unsigned packrowh(const float* __restrict__ W, int hp, int N, int c) {
    return pack2h(W[(2*hp)*N + c], W[(2*hp+1)*N + c]);
}

// ---- k_prep v2 (parallel fusions):
//   0..383   pack Whh/W1/W2
//   384..511 M1 = Wq@WkT pair-rows (+v1,w2,sc2)
//   512..639 M_ih = Wv@Wih, one pair-row per block (coalesced j-major)
//   640..642 bih' = bv@Wih + bih
__global__ __launch_bounds__(256) void k_prep(
        const float* __restrict__ Wq, const float* __restrict__ Wk,
        const float* __restrict__ bq, const float* __restrict__ bk,
        const float* __restrict__ Wv, const float* __restrict__ Wih,
        const float* __restrict__ Whh, const float* __restrict__ W1,
        const float* __restrict__ W2, const float* __restrict__ bih,
        const float* __restrict__ bv,
        unsigned* __restrict__ WhhP, unsigned* __restrict__ W1P,
        unsigned* __restrict__ W2P, unsigned* __restrict__ M1P,
        unsigned* __restrict__ M_ihP, float* __restrict__ bihP,
        float* __restrict__ v1, float* __restrict__ w2, float* __restrict__ sc2) {
    int t = threadIdx.x;
    if (blockIdx.x < 384) {
        int i = blockIdx.x * 256 + t;
        if (i < 65536) {
            int hp1 = i >> 9, c1 = i & 511;
            W1P[i] = packrowh(W1, hp1, 512, c1);
            int hp2 = i >> 8, c2 = i & 255;
            W2P[i] = packrowh(W2, hp2, 256, c2);
        }
        if (i < 98304) {
            int hp = i / 768, c = i % 768;
            WhhP[i] = packrowh(Whh, hp, 768, c);
        }
        return;
    }
    if (blockIdx.x < 512) {
        __shared__ float wq0[256], wq1[256], bqL[256];
        __shared__ float red4[4];
        int e2 = blockIdx.x - 384;
        wq0[t] = Wq[(2*e2)*256 + t];
        wq1[t] = Wq[(2*e2+1)*256 + t];
        bqL[t] = bq[t];
        __syncthreads();
        const float4* wkr = (const float4*)(Wk + (long)t * 256);
        float a0 = 0.f, a1 = 0.f;
        #pragma unroll 8
        for (int d = 0; d < 64; d++) {
            float4 k4 = wkr[d];
            a0 += wq0[4*d]*k4.x + wq0[4*d+1]*k4.y + wq0[4*d+2]*k4.z + wq0[4*d+3]*k4.w;
            a1 += wq1[4*d]*k4.x + wq1[4*d+1]*k4.y + wq1[4*d+2]*k4.z + wq1[4*d+3]*k4.w;
        }
        M1P[e2*256 + t] = pack2h(a0, a1);
        float p0 = blkred(wq0[t] * bk[t], red4);
        float p1 = blkred(wq1[t] * bk[t], red4);
        if (t == 0) { w2[2*e2] = p0; w2[2*e2+1] = p1; }
        if (e2 == 0) {
            float av = 0.f;
            #pragma unroll 8
            for (int d = 0; d < 64; d++) {
                float4 k4 = wkr[d];
                av += bqL[4*d]*k4.x + bqL[4*d+1]*k4.y + bqL[4*d+2]*k4.z + bqL[4*d+3]*k4.w;
            }
            v1[t] = av;
            float p2 = blkred(bqL[t] * bk[t], red4);
            if (t == 0) sc2[0] = p2;
        }
        return;
    }
    if (blockIdx.x < 640) {
        // M_ih pair-row hp = blockIdx-512: M_ih[h][j] = sum_c Wv[h][c]*Wih[c][j]
        __shared__ float w0[256], w1[256];
        int hp = blockIdx.x - 512;
        w0[t] = Wv[(2*hp)*256 + t];
        w1[t] = Wv[(2*hp+1)*256 + t];
        __syncthreads();
        #pragma unroll
        for (int jj = 0; jj < 3; jj++) {
            int j = jj * 256 + t;
            float a0 = 0.f, a1 = 0.f;
            #pragma unroll 8
            for (int c = 0; c < 256; c++) {
                float w = Wih[c*768 + j];
                a0 += w0[c] * w;
                a1 += w1[c] * w;
            }
            M_ihP[hp*768 + j] = pack2h(a0, a1);
        }
        return;
    }
    // bih' = bv@Wih + bih  (3 blocks, one j per thread)
    {
        int j = (blockIdx.x - 640) * 256 + t;
        float a = bih[j];
        #pragma unroll 8
        for (int c = 0; c < 256; c++) a += bv[c] * Wih[c*768 + j];
        bihP[j] = a;
    }
}

// ---- qk_tail (iter-0 only, fp32 weights) ----
__device__ __forceinline__ void qk_tail(
        float v0, float v1_, int b, int s0,
        const float* __restrict__ lng, const float* __restrict__ lnb,
        const float* __restrict__ Wq, const float* __restrict__ bq,
        const float* __restrict__ Wk, const float* __restrict__ bk,
        unsigned short* __restrict__ qkg, float* __restrict__ qbkg,
        float (*sh)[256], float (*red)[4]) {
    int c = threadIdx.x;
    float s_0 = v0, q_0 = v0 * v0, s_1 = v1_, q_1 = v1_ * v1_;
    #pragma unroll
    for (int m = 32; m; m >>= 1) {
        s_0 += __shfl_xor(s_0, m); q_0 += __shfl_xor(q_0, m);
        s_1 += __shfl_xor(s_1, m); q_1 += __shfl_xor(q_1, m);
    }
    if ((c & 63) == 0) { int w = c >> 6; red[w][0]=s_0; red[w][1]=q_0; red[w][2]=s_1; red[w][3]=q_1; }
    __syncthreads();
    float S0 = red[0][0]+red[1][0]+red[2][0]+red[3][0];
    float Q0 = red[0][1]+red[1][1]+red[2][1]+red[3][1];
    float S1 = red[0][2]+red[1][2]+red[2][2]+red[3][2];
    float Q1 = red[0][3]+red[1][3]+red[2][3]+red[3][3];
    float m0 = S0 * 0.00390625f, r0 = rsqrtf(Q0 * 0.00390625f - m0*m0 + 1e-5f);
    float m1 = S1 * 0.00390625f, r1 = rsqrtf(Q1 * 0.00390625f - m1*m1 + 1e-5f);
    float gc = lng[c], bc = lnb[c];
    sh[0][c] = (v0 - m0) * r0 * gc + bc;
    sh[1][c] = (v1_ - m1) * r1 * gc + bc;
    __syncthreads();
    float qa0 = bq[c], qa1 = qa0;
    for (int h = 0; h < 256; h += 4) {
        float w0 = Wq[(h+0)*256+c], w1 = Wq[(h+1)*256+c];
        float w2_ = Wq[(h+2)*256+c], w3 = Wq[(h+3)*256+c];
        float4 x0 = *(const float4*)&sh[0][h], x1 = *(const float4*)&sh[1][h];
        qa0 += x0.x*w0 + x0.y*w1 + x0.z*w2_ + x0.w*w3;
        qa1 += x1.x*w0 + x1.y*w1 + x1.z*w2_ + x1.w*w3;
    }
    __syncthreads();
    sh[0][c] = qa0; sh[1][c] = qa1;
    float bkc = bk[c];
    float p0 = qa0 * bkc, p1 = qa1 * bkc;
    #pragma unroll
    for (int m = 32; m; m >>= 1) { p0 += __shfl_xor(p0, m); p1 += __shfl_xor(p1, m); }
    __syncthreads();
    if ((c & 63) == 0) { int w = c >> 6; red[w][0] = p0; red[w][1] = p1; }
    __syncthreads();
    if (c < 2) qbkg[b*8 + s0 + c] = SCALE_F * (red[0][c]+red[1][c]+red[2][c]+red[3][c]);
    float k0 = 0.f, k1 = 0.f;
    const float* wkr = Wk + (long)c * 256;
    for (int d = 0; d < 256; d += 4) {
        float4 wk4 = *(const float4*)&wkr[d];
        float4 x0 = *(const float4*)&sh[0][d], x1 = *(const float4*)&sh[1][d];
        k0 += x0.x*wk4.x + x0.y*wk4.y + x0.z*wk4.z + x0.w*wk4.w;
        k1 += x1.x*wk4.x + x1.y*wk4.y + x1.z*wk4.z + x1.w*wk4.w;
    }
    qkg[(b*8 + s0    )*256 + c] = f2bf(SCALE_F * k0);
    qkg[(b*8 + s0 + 1)*256 + c] = f2bf(SCALE_F * k1);
}

__global__ __launch_bounds__(256) void k_init(
        const float* __restrict__ noise, const float* __restrict__ mu,
        const float* __restrict__ sig, const float* __restrict__ lng,
        const float* __restrict__ lnb, const float* __restrict__ Wq,
        const float* __restrict__ bq, const float* __restrict__ Wk,
        const float* __restrict__ bk, float* __restrict__ slots,
        unsigned short* __restrict__ qkg, float* __restrict__ qbkg) {
    __shared__ float sh[2][256];
    __shared__ float red[4][4];
    int b = blockIdx.x >> 2, rp = blockIdx.x & 3;
    int s0 = rp * 2, r0 = b * 8 + s0;
    int c = threadIdx.x;
    float v0 = mu[c] + sig[c] * noise[r0*256 + c];
    float v1 = mu[c] + sig[c] * noise[(r0+1)*256 + c];
    slots[r0*256 + c] = v0;
    slots[(r0+1)*256 + c] = v1;
    qk_tail(v0, v1, b, s0, lng, lnb, Wq, bq, Wk, bk, qkg, qbkg, sh, red);
}

// ------- streaming attention (R7 version, proven) -------
__global__ __launch_bounds__(128) void k_stream(
        const unsigned short* __restrict__ lnx, const unsigned short* __restrict__ qk,
        const float* __restrict__ qbk, float* __restrict__ Upart,
        float* __restrict__ dpart) {
    __shared__ unsigned short xt[TPOS * 256];
    __shared__ float Ured[8 * 256];
    __shared__ float dred[8];
    int b = blockIdx.x >> 5, ch = blockIdx.x & 31;
    int t = threadIdx.x;
    int l = t & 63, w = t >> 6;
    for (int i = t; i < 2048; i += 128) Ured[i] = 0.f;
    if (t < 8) dred[t] = 0.f;
    int slot = l & 15, g = l >> 4;
    s16x8 qkf[8];
    float qbkv = 0.f;
    if (slot < 8) {
        const unsigned short* qrow = qk + (b*8 + slot) * 256;
        #pragma unroll
        for (int hk = 0; hk < 8; hk++)
            qkf[hk] = *(const s16x8*)(qrow + hk*32 + 8*g);
        qbkv = qbk[b*8 + slot];
    } else {
        #pragma unroll
        for (int hk = 0; hk < 8; hk++) qkf[hk] = (s16x8)0;
    }
    f32x4 uacc[16];
    #pragma unroll
    for (int i = 0; i < 16; i++) uacc[i] = (f32x4)0.f;
    float dreg = 0.f;
    int gbase = (b * NPOS + ch * CPOS) * 256;
    int pw = w * 16;
    __syncthreads();
    for (int tile = 0; tile < 4; tile++) {
        #pragma unroll
        for (int i = 0; i < 8; i++) {
            int c = t + 128 * i;
            int p = c >> 5, hc = c & 31;
            int4 v = *(const int4*)(lnx + gbase + (tile*TPOS + p)*256 + hc*8);
            *(int4*)&xt[p*256 + ((hc ^ (p & 15)) << 3)] = v;
        }
        __syncthreads();
        f32x4 acc = (f32x4)0.f;
        {
            int prow = pw + (l & 15);
            const unsigned short* xrow = &xt[prow * 256];
            int sw = prow & 15;
            #pragma unroll
            for (int hk = 0; hk < 8; hk++) {
                s16x8 a = *(const s16x8*)(xrow + (((hk*4 + g) ^ sw) << 3));
                acc = __builtin_amdgcn_mfma_f32_16x16x32_bf16(a, qkf[hk], acc, 0, 0, 0);
            }
        }
        float at[4];
        #pragma unroll
        for (int r = 0; r < 4; r++) {
            float v = acc[r] + qbkv;
            float m = v;
            m = fmaxf(m, __shfl_xor(m, 1));
            m = fmaxf(m, __shfl_xor(m, 2));
            m = fmaxf(m, __shfl_xor(m, 4));
            float e = __expf(v - m);
            float sum = e;
            sum += __shfl_xor(sum, 1);
            sum += __shfl_xor(sum, 2);
            sum += __shfl_xor(sum, 4);
            float a = e / sum;
            at[r] = a;
            dreg += a;
        }
        u32x2 a2;
        a2.x = (unsigned)f2bf(at[0]) | ((unsigned)f2bf(at[1]) << 16);
        a2.y = (unsigned)f2bf(at[2]) | ((unsigned)f2bf(at[3]) << 16);
        int p0 = pw + 4 * g;
        int hl = l & 7;
        #pragma unroll
        for (int hc = 0; hc < 16; hc++) {
            int hcol = hc * 2 + ((l & 15) >> 3);
            unsigned e0 = xt[(p0+0)*256 + ((hcol ^ ((p0+0) & 15)) << 3) + hl];
            unsigned e1 = xt[(p0+1)*256 + ((hcol ^ ((p0+1) & 15)) << 3) + hl];
            unsigned e2 = xt[(p0+2)*256 + ((hcol ^ ((p0+2) & 15)) << 3) + hl];
            unsigned e3 = xt[(p0+3)*256 + ((hcol ^ ((p0+3) & 15)) << 3) + hl];
            u32x2 b2;
            b2.x = e0 | (e1 << 16);
            b2.y = e2 | (e3 << 16);
            asm volatile("v_mfma_f32_16x16x16_bf16 %0, %1, %2, %0"
                         : "+v"(uacc[hc]) : "v"(a2), "v"(b2));
        }
        __syncthreads();
    }
    if (g < 2) {
        #pragma unroll
        for (int hc = 0; hc < 16; hc++) {
            int h = hc * 16 + (l & 15);
            #pragma unroll
            for (int r = 0; r < 4; r++)
                atomicAdd(&Ured[(4*g + r)*256 + h], uacc[hc][r]);
        }
    }
    dreg += __shfl_xor(dreg, 16);
    dreg += __shfl_xor(dreg, 32);
    if (slot < 8 && g == 0) atomicAdd(&dred[slot], dreg);
    __syncthreads();
    float* up = Upart + (long)(b * NCHUNK + ch) * 2048;
    for (int i = t; i < 2048; i += 128) up[i] = Ured[i];
    if (t < 8) dpart[(b * NCHUNK + ch) * 8 + t] = dred[t];
}

// ---- 1024-thread duplicated-column layernorm ----
__device__ __forceinline__ float ln1024(float v, int c, const float* __restrict__ g,
                                        const float* __restrict__ b, float (*red)[2]) {
    float s1 = v, s2 = v * v;
    #pragma unroll
    for (int m = 32; m; m >>= 1) { s1 += __shfl_xor(s1, m); s2 += __shfl_xor(s2, m); }
    int w = threadIdx.x >> 6;
    if ((threadIdx.x & 63) == 0) { red[w][0] = s1; red[w][1] = s2; }
    __syncthreads();
    float S = 0.f, Q = 0.f;
    #pragma unroll
    for (int i = 0; i < 16; i++) { S += red[i][0]; Q += red[i][1]; }
    float mean = S * (1.f/1024.f);
    float rstd = rsqrtf(Q * (1.f/1024.f) - mean*mean + 1e-5f);
    __syncthreads();
    return (v - mean) * rstd * g[c] + b[c];
}

// ---- k_post v8: 1 row/block, 1024 threads, fused M_ih/M1 weights ----
__global__ __launch_bounds__(1024) void k_post(
        const float* __restrict__ Upart, const float* __restrict__ dpart,
        const unsigned* __restrict__ M_ihP, const unsigned* __restrict__ WhhP,
        const float* __restrict__ bihP, const float* __restrict__ bhh,
        const float* __restrict__ lnmg, const float* __restrict__ lnmb,
        const unsigned* __restrict__ W1P, const float* __restrict__ b1,
        const unsigned* __restrict__ W2P, const float* __restrict__ b2,
        const float* __restrict__ lnsg, const float* __restrict__ lnsb,
        const unsigned* __restrict__ M1P, const float* __restrict__ v1g,
        const float* __restrict__ w2g, const float* __restrict__ sc2g,
        float* __restrict__ slots, unsigned short* __restrict__ qkg,
        float* __restrict__ qbkg, float* __restrict__ outp, int last) {
    __shared__ union {
        float PG[2][8][768];
        struct { float P16[16][256]; float H2[8][512]; } s;
    } sm;
    __shared__ float A[256], B[256], G2[2][768], H[512];
    __shared__ float red[16][2];
    __shared__ float scal[1];
    int r = blockIdx.x, b = r >> 3, s = r & 7;
    int t = threadIdx.x, c = t & 255, q = t >> 8;
    int cg = t & 63, kg16 = t >> 6;
    // Phase 1: U reduce + denom + slots
    {
        float u = 0.f;
        const float* ub = Upart + (long)b * NCHUNK * 2048 + s * 256 + c;
        #pragma unroll
        for (int i = 0; i < 8; i++) u += ub[(q * 8 + i) * 2048];
        sm.s.P16[q][c] = u;
        if (q == 1) B[c] = slots[r * 256 + c];
        if (t < 32) {
            float dv = dpart[(b * NCHUNK + t) * 8 + s];
            #pragma unroll
            for (int m = 16; m; m >>= 1) dv += __shfl_xor(dv, m);
            if (t == 0) scal[0] = dv;
        }
    }
    __syncthreads();
    float dn = 1.f / (scal[0] + (float)NPOS * EPS_F);
    if (q == 0)
        A[c] = (sm.s.P16[0][c] + sm.s.P16[1][c] + sm.s.P16[2][c] + sm.s.P16[3][c]) * dn;
    __syncthreads();
    // Phase 2: GRU partials (gi via M_ih on A=U/den; gh via Whh on B=slots)
    {
        int h = t >> 9;
        int kg = (t >> 6) & 7;
        const float* src = h ? B : A;
        const unsigned* W = h ? WhhP : M_ihP;
        f32x4 ar = (f32x4)0.f, az = (f32x4)0.f, an = (f32x4)0.f;
        #pragma unroll 4
        for (int i = 0; i < 16; i++) {
            int hp = kg * 16 + i;
            h16x2 av = mkh(src[2*hp], src[2*hp+1]);
            uint4 w0 = *(const uint4*)(W + hp*768 + 4*cg);
            uint4 w1 = *(const uint4*)(W + hp*768 + 256 + 4*cg);
            uint4 w2 = *(const uint4*)(W + hp*768 + 512 + 4*cg);
            dot4(ar, w0, av);
            dot4(az, w1, av);
            dot4(an, w2, av);
        }
        *(f32x4*)&sm.PG[h][kg][4*cg]       = ar;
        *(f32x4*)&sm.PG[h][kg][256 + 4*cg] = az;
        *(f32x4*)&sm.PG[h][kg][512 + 4*cg] = an;
    }
    __syncthreads();
    for (int idx = t; idx < 1536; idx += 1024) {
        int h = idx / 768, cc = idx - h * 768;
        float ss = 0.f;
        #pragma unroll
        for (int k = 0; k < 8; k++) ss += sm.PG[h][k][cc];
        G2[h][cc] = ss;
    }
    __syncthreads();
    // GRU elementwise (bih' folded constant)
    float spc = B[c];
    float gir = bihP[c]     + G2[0][c];
    float giz = bihP[c+256] + G2[0][c+256];
    float gin = bihP[c+512] + G2[0][c+512];
    float ghr = bhh[c]      + G2[1][c];
    float ghz = bhh[c+256]  + G2[1][c+256];
    float ghn = bhh[c+512]  + G2[1][c+512];
    float rg = 1.f/(1.f + __expf(-(gir+ghr)));
    float zg = 1.f/(1.f + __expf(-(giz+ghz)));
    float ng = tanhf(gin + rg*ghn);
    float hnew = (1.f - zg)*ng + zg*spc;
    float mmc = ln1024(hnew, c, lnmg, lnmb, red);
    if (q == 0) A[c] = mmc;
    __syncthreads();
    // MLP1
    {
        int kg = t >> 7, cg1 = t & 127;
        f32x4 acc = (f32x4)0.f;
        const uint4* wp = (const uint4*)(W1P + kg * 16 * 512 + 4 * cg1);
        #pragma unroll 4
        for (int i = 0; i < 16; i++) {
            uint4 wv = wp[i * 128];
            dot4(acc, wv, mkh(A[2*(kg*16+i)], A[2*(kg*16+i)+1]));
        }
        *(f32x4*)&sm.s.H2[kg][4*cg1] = acc;
    }
    __syncthreads();
    if (t < 512) {
        float ss = b1[t];
        #pragma unroll
        for (int k = 0; k < 8; k++) ss += sm.s.H2[k][t];
        H[t] = fmaxf(ss, 0.f);
    }
    __syncthreads();
    // MLP2 + residual
    {
        f32x4 acc = (f32x4)0.f;
        const uint4* wp = (const uint4*)(W2P + kg16 * 16 * 256 + 4 * cg);
        #pragma unroll 4
        for (int i = 0; i < 16; i++) {
            uint4 wv = wp[i * 64];
            dot4(acc, wv, mkh(H[2*(kg16*16+i)], H[2*(kg16*16+i)+1]));
        }
        *(f32x4*)&sm.s.P16[kg16][4*cg] = acc;
    }
    __syncthreads();
    float outc;
    {
        float ss = 0.f;
        #pragma unroll
        for (int k = 0; k < 16; k++) ss += sm.s.P16[k][c];
        outc = hnew + ss + b2[c];
    }
    if (t < 256) {
        slots[r*256 + c] = outc;
        if (last) outp[r*256 + c] = outc;
    }
    if (last) return;
    __syncthreads();
    // qk tail: LN -> qbk (w2/sc2) -> qk = sc@M1 + v1
    float sc = ln1024(outc, c, lnsg, lnsb, red);
    if (q == 0) A[c] = sc;
    {
        float v = sc * w2g[c];
        #pragma unroll
        for (int m = 32; m; m >>= 1) v += __shfl_xor(v, m);
        int w = t >> 6;
        if ((t & 63) == 0) red[w][0] = v;
    }
    __syncthreads();
    if (t == 0) {
        float S = 0.f;
        #pragma unroll
        for (int i = 0; i < 16; i++) S += red[i][0];
        qbkg[r] = SCALE_F * (0.25f * S + sc2g[0]);
    }
    {
        f32x4 acc = (f32x4)0.f;
        const uint4* wp = (const uint4*)(M1P + kg16 * 8 * 256 + 4 * cg);
        #pragma unroll
        for (int i = 0; i < 8; i++) {
            uint4 wv = wp[i * 64];
            dot4(acc, wv, mkh(A[2*(kg16*8+i)], A[2*(kg16*8+i)+1]));
        }
        *(f32x4*)&sm.s.P16[kg16][4*cg] = acc;
    }
    __syncthreads();
    if (t < 256) {
        float ss = 0.f;
        #pragma unroll
        for (int k = 0; k < 16; k++) ss += sm.s.P16[k][c];
        qkg[r*256 + c] = f2bf(SCALE_F * (ss + v1g[c]));
    }
}

extern "C" void kernel_launch(void* const* d_in, const int* in_sizes, int n_in,
                              void* d_out, int out_size, void* d_ws, size_t ws_size,
                              hipStream_t stream) {
    const float* inputs = (const float*)d_in[0];
    const float* noise  = (const float*)d_in[1];
    const float* mu     = (const float*)d_in[2];
    const float* sig    = (const float*)d_in[3];
    const float* lnig   = (const float*)d_in[4];
    const float* lnib   = (const float*)d_in[5];
    const float* lnsg   = (const float*)d_in[6];
    const float* lnsb   = (const float*)d_in[7];
    const float* lnmg   = (const float*)d_in[8];
    const float* lnmb   = (const float*)d_in[9];
    const float* Wq     = (const float*)d_in[10];
    const float* bq     = (const float*)d_in[11];
    const float* Wk     = (const float*)d_in[12];
    const float* bk     = (const float*)d_in[13];
    const float* Wv     = (const float*)d_in[14];
    const float* bv     = (const float*)d_in[15];
    const float* Wih    = (const float*)d_in[16];
    const float* Whh    = (const float*)d_in[17];
    const float* bih    = (const float*)d_in[18];
    const float* bhh    = (const float*)d_in[19];
    const float* W1     = (const float*)d_in[20];
    const float* b1     = (const float*)d_in[21];
    const float* W2     = (const float*)d_in[22];
    const float* b2     = (const float*)d_in[23];

    char* ws = (char*)d_ws;
    unsigned short* lnx = (unsigned short*)ws;
    size_t off = (size_t)NB * NPOS * HIDD * 2;                                   // 64 MB
    unsigned short* qkb = (unsigned short*)(ws + off); off += (size_t)NB*NSLOT*HIDD*2;
    float* qbk   = (float*)(ws + off); off += (size_t)NB*NSLOT*4;
    float* Upart = (float*)(ws + off); off += (size_t)NB*NCHUNK*NSLOT*HIDD*4;    // 8 MB
    float* dpart = (float*)(ws + off); off += (size_t)NB*NCHUNK*NSLOT*4;
    float* slots = (float*)(ws + off); off += (size_t)NB*NSLOT*DDIM*4;
    unsigned* WhhP  = (unsigned*)(ws + off); off += 98304u*4;
    unsigned* W1P   = (unsigned*)(ws + off); off += 65536u*4;
    unsigned* W2P   = (unsigned*)(ws + off); off += 65536u*4;
    unsigned* M1P   = (unsigned*)(ws + off); off += 32768u*4;
    unsigned* M_ihP = (unsigned*)(ws + off); off += 98304u*4;
    float* bihP = (float*)(ws + off); off += 768*4;
    float* v1   = (float*)(ws + off); off += 256*4;
    float* w2   = (float*)(ws + off); off += 256*4;
    float* sc2  = (float*)(ws + off); off += 64;

    k_prep<<<643, 256, 0, stream>>>(Wq, Wk, bq, bk, Wv, Wih, Whh, W1, W2, bih, bv,
                                    WhhP, W1P, W2P, M1P, M_ihP, bihP, v1, w2, sc2);
    k_ln_in<<<NB*NPOS/4, 256, 0, stream>>>(inputs, lnig, lnib, lnx);
    k_init<<<NB*4, 256, 0, stream>>>(noise, mu, sig, lnsg, lnsb, Wq, bq, Wk, bk,
                                     slots, qkb, qbk);
    for (int it = 0; it < 3; it++) {
        k_stream<<<NB*NCHUNK, 128, 0, stream>>>(lnx, qkb, qbk, Upart, dpart);
        k_post<<<NB*NSLOT, 1024, 0, stream>>>(Upart, dpart,
                                              M_ihP, WhhP, bihP, bhh,
                                              lnmg, lnmb, W1P, b1, W2P, b2,
                                              lnsg, lnsb, M1P, v1, w2, sc2,
                                              slots, qkb, qbk, (float*)d_out,
                                              it == 2 ? 1 : 0);
    }
}

// Round 13
// 216.052 us; speedup vs baseline: 1.3418x; 1.2096x over previous
//
#include <hip/hip_runtime.h>
#include <hip/hip_bf16.h>

#define NB 32
#define NPOS 4096
#define NSLOT 8
#define HIDD 256
#define DDIM 256
#define SCALE_F 0.0625f
#define EPS_F 1e-8f
#define NCHUNK 32
#define CPOS 128
#define TPOS 32

typedef __attribute__((ext_vector_type(4))) float f32x4;
typedef __attribute__((ext_vector_type(8))) short s16x8;
typedef __attribute__((ext_vector_type(2))) unsigned int u32x2;
typedef _Float16 h16x2 __attribute__((ext_vector_type(2)));

__device__ __forceinline__ unsigned short f2bf(float f) {
    unsigned int x = __float_as_uint(f);
    x = (x + 0x7fffu + ((x >> 16) & 1u)) >> 16;
    return (unsigned short)x;
}
__device__ __forceinline__ unsigned short f2h(float f) {
    _Float16 h = (_Float16)f;
    return __builtin_bit_cast(unsigned short, h);
}
__device__ __forceinline__ h16x2 u2h(unsigned u) { return __builtin_bit_cast(h16x2, u); }
__device__ __forceinline__ h16x2 mkh(float a0, float a1) {
    h16x2 r; r[0] = (_Float16)a0; r[1] = (_Float16)a1; return r;
}
__device__ __forceinline__ void dot4(f32x4& acc, uint4 wv, h16x2 av) {
    acc[0] = __builtin_amdgcn_fdot2(av, u2h(wv.x), acc[0], false);
    acc[1] = __builtin_amdgcn_fdot2(av, u2h(wv.y), acc[1], false);
    acc[2] = __builtin_amdgcn_fdot2(av, u2h(wv.z), acc[2], false);
    acc[3] = __builtin_amdgcn_fdot2(av, u2h(wv.w), acc[3], false);
}
__device__ __forceinline__ unsigned packrowh(const float* __restrict__ W, int hp, int N, int c) {
    return (unsigned)f2h(W[(2*hp)*N + c]) | ((unsigned)f2h(W[(2*hp+1)*N + c]) << 16);
}

// ---- qk_tail (iter-0 slot init path, fp32 weights) ----
__device__ __forceinline__ void qk_tail(
        float v0, float v1, int b, int s0,
        const float* __restrict__ lng, const float* __restrict__ lnb,
        const float* __restrict__ Wq, const float* __restrict__ bq,
        const float* __restrict__ Wk, const float* __restrict__ bk,
        unsigned short* __restrict__ qkg, float* __restrict__ qbkg,
        float (*sh)[256], float (*red)[4]) {
    int c = threadIdx.x;
    float s_0 = v0, q_0 = v0 * v0, s_1 = v1, q_1 = v1 * v1;
    #pragma unroll
    for (int m = 32; m; m >>= 1) {
        s_0 += __shfl_xor(s_0, m); q_0 += __shfl_xor(q_0, m);
        s_1 += __shfl_xor(s_1, m); q_1 += __shfl_xor(q_1, m);
    }
    if ((c & 63) == 0) { int w = c >> 6; red[w][0]=s_0; red[w][1]=q_0; red[w][2]=s_1; red[w][3]=q_1; }
    __syncthreads();
    float S0 = red[0][0]+red[1][0]+red[2][0]+red[3][0];
    float Q0 = red[0][1]+red[1][1]+red[2][1]+red[3][1];
    float S1 = red[0][2]+red[1][2]+red[2][2]+red[3][2];
    float Q1 = red[0][3]+red[1][3]+red[2][3]+red[3][3];
    float m0 = S0 * 0.00390625f, r0 = rsqrtf(Q0 * 0.00390625f - m0*m0 + 1e-5f);
    float m1 = S1 * 0.00390625f, r1 = rsqrtf(Q1 * 0.00390625f - m1*m1 + 1e-5f);
    float gc = lng[c], bc = lnb[c];
    sh[0][c] = (v0 - m0) * r0 * gc + bc;
    sh[1][c] = (v1 - m1) * r1 * gc + bc;
    __syncthreads();
    float qa0 = bq[c], qa1 = qa0;
    for (int h = 0; h < 256; h += 4) {
        float w0 = Wq[(h+0)*256+c], w1 = Wq[(h+1)*256+c];
        float w2 = Wq[(h+2)*256+c], w3 = Wq[(h+3)*256+c];
        float4 x0 = *(const float4*)&sh[0][h], x1 = *(const float4*)&sh[1][h];
        qa0 += x0.x*w0 + x0.y*w1 + x0.z*w2 + x0.w*w3;
        qa1 += x1.x*w0 + x1.y*w1 + x1.z*w2 + x1.w*w3;
    }
    __syncthreads();
    sh[0][c] = qa0; sh[1][c] = qa1;
    float bkc = bk[c];
    float p0 = qa0 * bkc, p1 = qa1 * bkc;
    #pragma unroll
    for (int m = 32; m; m >>= 1) { p0 += __shfl_xor(p0, m); p1 += __shfl_xor(p1, m); }
    __syncthreads();
    if ((c & 63) == 0) { int w = c >> 6; red[w][0] = p0; red[w][1] = p1; }
    __syncthreads();
    if (c < 2) qbkg[b*8 + s0 + c] = SCALE_F * (red[0][c]+red[1][c]+red[2][c]+red[3][c]);
    float k0 = 0.f, k1 = 0.f;
    const float* wkr = Wk + (long)c * 256;
    for (int d = 0; d < 256; d += 4) {
        float4 wk4 = *(const float4*)&wkr[d];
        float4 x0 = *(const float4*)&sh[0][d], x1 = *(const float4*)&sh[1][d];
        k0 += x0.x*wk4.x + x0.y*wk4.y + x0.z*wk4.z + x0.w*wk4.w;
        k1 += x1.x*wk4.x + x1.y*wk4.y + x1.z*wk4.z + x1.w*wk4.w;
    }
    qkg[(b*8 + s0    )*256 + c] = f2bf(SCALE_F * k0);
    qkg[(b*8 + s0 + 1)*256 + c] = f2bf(SCALE_F * k1);
}

// ==== k_setup: one dispatch doing ln_in [0,8192) + weight-pack [8192,8576) + init [8576,8704) ====
__global__ __launch_bounds__(256) void k_setup(
        const float* __restrict__ x, const float* __restrict__ lnig,
        const float* __restrict__ lnib, unsigned short* __restrict__ lnx,
        const float* __restrict__ Wq, const float* __restrict__ Wk,
        const float* __restrict__ Wv, const float* __restrict__ Wih,
        const float* __restrict__ Whh, const float* __restrict__ W1,
        const float* __restrict__ W2,
        unsigned* __restrict__ WqP, unsigned* __restrict__ WkTP,
        unsigned* __restrict__ WvP, unsigned* __restrict__ WihP,
        unsigned* __restrict__ WhhP, unsigned* __restrict__ W1P,
        unsigned* __restrict__ W2P,
        const float* __restrict__ noise, const float* __restrict__ mu,
        const float* __restrict__ sig, const float* __restrict__ lnsg,
        const float* __restrict__ lnsb, const float* __restrict__ bq,
        const float* __restrict__ bk, float* __restrict__ slots,
        unsigned short* __restrict__ qkg, float* __restrict__ qbkg) {
    __shared__ float sh[2][256];
    __shared__ float red[4][4];
    if (blockIdx.x < 8192) {
        // ---- LayerNorm(inputs) -> bf16, one wave per row ----
        int lane = threadIdx.x & 63;
        int wave = threadIdx.x >> 6;
        long row = (long)blockIdx.x * 4 + wave;
        const float4* xr = (const float4*)(x + row * 256);
        float4 v = xr[lane];
        float s = v.x + v.y + v.z + v.w;
        float sq = v.x * v.x + v.y * v.y + v.z * v.z + v.w * v.w;
        #pragma unroll
        for (int m = 32; m; m >>= 1) { s += __shfl_xor(s, m); sq += __shfl_xor(sq, m); }
        float mean = s * 0.00390625f;
        float rstd = rsqrtf(sq * 0.00390625f - mean * mean + 1e-5f);
        const float4 gg = ((const float4*)lnig)[lane];
        const float4 bb = ((const float4*)lnib)[lane];
        ushort4 o;
        o.x = f2bf((v.x - mean) * rstd * gg.x + bb.x);
        o.y = f2bf((v.y - mean) * rstd * gg.y + bb.y);
        o.z = f2bf((v.z - mean) * rstd * gg.z + bb.z);
        o.w = f2bf((v.w - mean) * rstd * gg.w + bb.w);
        ((ushort4*)(lnx + row * 256))[lane] = o;
        return;
    }
    if (blockIdx.x < 8576) {
        // ---- weight pack (f16 row-pair packed) ----
        int i = (blockIdx.x - 8192) * 256 + threadIdx.x;
        if (i < 32768) {
            int hp = i >> 8, c = i & 255;
            WqP[i] = packrowh(Wq, hp, 256, c);
            WvP[i] = packrowh(Wv, hp, 256, c);
            WkTP[i] = (unsigned)f2h(Wk[c*256 + 2*hp]) | ((unsigned)f2h(Wk[c*256 + 2*hp + 1]) << 16);
        }
        if (i < 65536) {
            int hp1 = i >> 9, c1 = i & 511;
            W1P[i] = packrowh(W1, hp1, 512, c1);
            int hp2 = i >> 8, c2 = i & 255;
            W2P[i] = packrowh(W2, hp2, 256, c2);
        }
        if (i < 98304) {
            int hp = i / 768, c = i % 768;
            WihP[i] = packrowh(Wih, hp, 768, c);
            WhhP[i] = packrowh(Whh, hp, 768, c);
        }
        return;
    }
    // ---- iter-0 slots init + LN + q + qk ----
    {
        int bi = blockIdx.x - 8576;
        int b = bi >> 2, rp = bi & 3;
        int s0 = rp * 2, r0 = b * 8 + s0;
        int c = threadIdx.x;
        float v0 = mu[c] + sig[c] * noise[r0*256 + c];
        float v1 = mu[c] + sig[c] * noise[(r0+1)*256 + c];
        slots[r0*256 + c] = v0;
        slots[(r0+1)*256 + c] = v1;
        qk_tail(v0, v1, b, s0, lnsg, lnsb, Wq, bq, Wk, bk, qkg, qbkg, sh, red);
    }
}

// ------- streaming attention: MFMA dots -> softmax(slot) -> MFMA updates (R7, proven) -------
__global__ __launch_bounds__(128) void k_stream(
        const unsigned short* __restrict__ lnx, const unsigned short* __restrict__ qk,
        const float* __restrict__ qbk, float* __restrict__ Upart,
        float* __restrict__ dpart) {
    __shared__ unsigned short xt[TPOS * 256];
    __shared__ float Ured[8 * 256];
    __shared__ float dred[8];
    int b = blockIdx.x >> 5, ch = blockIdx.x & 31;
    int t = threadIdx.x;
    int l = t & 63, w = t >> 6;
    for (int i = t; i < 2048; i += 128) Ured[i] = 0.f;
    if (t < 8) dred[t] = 0.f;
    int slot = l & 15, g = l >> 4;
    s16x8 qkf[8];
    float qbkv = 0.f;
    if (slot < 8) {
        const unsigned short* qrow = qk + (b*8 + slot) * 256;
        #pragma unroll
        for (int hk = 0; hk < 8; hk++)
            qkf[hk] = *(const s16x8*)(qrow + hk*32 + 8*g);
        qbkv = qbk[b*8 + slot];
    } else {
        #pragma unroll
        for (int hk = 0; hk < 8; hk++) qkf[hk] = (s16x8)0;
    }
    f32x4 uacc[16];
    #pragma unroll
    for (int i = 0; i < 16; i++) uacc[i] = (f32x4)0.f;
    float dreg = 0.f;
    int gbase = (b * NPOS + ch * CPOS) * 256;
    int pw = w * 16;
    __syncthreads();
    for (int tile = 0; tile < 4; tile++) {
        #pragma unroll
        for (int i = 0; i < 8; i++) {
            int c = t + 128 * i;
            int p = c >> 5, hc = c & 31;
            int4 v = *(const int4*)(lnx + gbase + (tile*TPOS + p)*256 + hc*8);
            *(int4*)&xt[p*256 + ((hc ^ (p & 15)) << 3)] = v;
        }
        __syncthreads();
        f32x4 acc = (f32x4)0.f;
        {
            int prow = pw + (l & 15);
            const unsigned short* xrow = &xt[prow * 256];
            int sw = prow & 15;
            #pragma unroll
            for (int hk = 0; hk < 8; hk++) {
                s16x8 a = *(const s16x8*)(xrow + (((hk*4 + g) ^ sw) << 3));
                acc = __builtin_amdgcn_mfma_f32_16x16x32_bf16(a, qkf[hk], acc, 0, 0, 0);
            }
        }
        float at[4];
        #pragma unroll
        for (int r = 0; r < 4; r++) {
            float v = acc[r] + qbkv;
            float m = v;
            m = fmaxf(m, __shfl_xor(m, 1));
            m = fmaxf(m, __shfl_xor(m, 2));
            m = fmaxf(m, __shfl_xor(m, 4));
            float e = __expf(v - m);
            float sum = e;
            sum += __shfl_xor(sum, 1);
            sum += __shfl_xor(sum, 2);
            sum += __shfl_xor(sum, 4);
            float a = e / sum;
            at[r] = a;
            dreg += a;
        }
        u32x2 a2;
        a2.x = (unsigned)f2bf(at[0]) | ((unsigned)f2bf(at[1]) << 16);
        a2.y = (unsigned)f2bf(at[2]) | ((unsigned)f2bf(at[3]) << 16);
        int p0 = pw + 4 * g;
        int hl = l & 7;
        #pragma unroll
        for (int hc = 0; hc < 16; hc++) {
            int hcol = hc * 2 + ((l & 15) >> 3);
            unsigned e0 = xt[(p0+0)*256 + ((hcol ^ ((p0+0) & 15)) << 3) + hl];
            unsigned e1 = xt[(p0+1)*256 + ((hcol ^ ((p0+1) & 15)) << 3) + hl];
            unsigned e2 = xt[(p0+2)*256 + ((hcol ^ ((p0+2) & 15)) << 3) + hl];
            unsigned e3 = xt[(p0+3)*256 + ((hcol ^ ((p0+3) & 15)) << 3) + hl];
            u32x2 b2;
            b2.x = e0 | (e1 << 16);
            b2.y = e2 | (e3 << 16);
            asm volatile("v_mfma_f32_16x16x16_bf16 %0, %1, %2, %0"
                         : "+v"(uacc[hc]) : "v"(a2), "v"(b2));
        }
        __syncthreads();
    }
    if (g < 2) {
        #pragma unroll
        for (int hc = 0; hc < 16; hc++) {
            int h = hc * 16 + (l & 15);
            #pragma unroll
            for (int r = 0; r < 4; r++)
                atomicAdd(&Ured[(4*g + r)*256 + h], uacc[hc][r]);
        }
    }
    dreg += __shfl_xor(dreg, 16);
    dreg += __shfl_xor(dreg, 32);
    if (slot < 8 && g == 0) atomicAdd(&dred[slot], dreg);
    __syncthreads();
    float* up = Upart + (long)(b * NCHUNK + ch) * 2048;
    for (int i = t; i < 2048; i += 128) up[i] = Ured[i];
    if (t < 8) dpart[(b * NCHUNK + ch) * 8 + t] = dred[t];
}

// ---- 1024-thread duplicated-column layernorm ----
__device__ __forceinline__ float ln1024(float v, int c, const float* __restrict__ g,
                                        const float* __restrict__ b, float (*red)[2]) {
    float s1 = v, s2 = v * v;
    #pragma unroll
    for (int m = 32; m; m >>= 1) { s1 += __shfl_xor(s1, m); s2 += __shfl_xor(s2, m); }
    int w = threadIdx.x >> 6;
    if ((threadIdx.x & 63) == 0) { red[w][0] = s1; red[w][1] = s2; }
    __syncthreads();
    float S = 0.f, Q = 0.f;
    #pragma unroll
    for (int i = 0; i < 16; i++) { S += red[i][0]; Q += red[i][1]; }
    float mean = S * (1.f/1024.f);
    float rstd = rsqrtf(Q * (1.f/1024.f) - mean*mean + 1e-5f);
    __syncthreads();
    return (v - mean) * rstd * g[c] + b[c];
}

// ---- k_post (R7 v6, proven): 1 row/block, 1024 threads, f16 weights + fdot2 ----
__global__ __launch_bounds__(1024) void k_post(
        const float* __restrict__ Upart, const float* __restrict__ dpart,
        const unsigned* __restrict__ WvP, const float* __restrict__ bv,
        const unsigned* __restrict__ WihP, const unsigned* __restrict__ WhhP,
        const float* __restrict__ bih, const float* __restrict__ bhh,
        const float* __restrict__ lnmg, const float* __restrict__ lnmb,
        const unsigned* __restrict__ W1P, const float* __restrict__ b1,
        const unsigned* __restrict__ W2P, const float* __restrict__ b2,
        const float* __restrict__ lnsg, const float* __restrict__ lnsb,
        const unsigned* __restrict__ WqP, const float* __restrict__ bq,
        const unsigned* __restrict__ WkTP, const float* __restrict__ bk,
        float* __restrict__ slots, unsigned short* __restrict__ qkg,
        float* __restrict__ qbkg, float* __restrict__ outp, int last) {
    __shared__ union {
        float PG[2][8][768];
        struct { float P16[16][256]; float H2[8][512]; } s;
    } sm;
    __shared__ float A[256], B[256], G2[2][768], H[512];
    __shared__ float red[16][2];
    __shared__ float scal[1];
    int r = blockIdx.x, b = r >> 3, s = r & 7;
    int t = threadIdx.x, c = t & 255, q = t >> 8;
    int cg = t & 63, kg16 = t >> 6;
    {
        float u = 0.f;
        const float* ub = Upart + (long)b * NCHUNK * 2048 + s * 256 + c;
        #pragma unroll
        for (int i = 0; i < 8; i++) u += ub[(q * 8 + i) * 2048];
        sm.s.P16[q][c] = u;
        if (q == 1) B[c] = slots[r * 256 + c];
        if (t < 32) {
            float dv = dpart[(b * NCHUNK + t) * 8 + s];
            #pragma unroll
            for (int m = 16; m; m >>= 1) dv += __shfl_xor(dv, m);
            if (t == 0) scal[0] = dv;
        }
    }
    __syncthreads();
    float dn = 1.f / (scal[0] + (float)NPOS * EPS_F);
    if (q == 0) A[c] = sm.s.P16[0][c] + sm.s.P16[1][c] + sm.s.P16[2][c] + sm.s.P16[3][c];
    __syncthreads();
    {
        f32x4 acc = (f32x4)0.f;
        const uint4* wp = (const uint4*)(WvP + kg16 * 8 * 256 + 4 * cg);
        #pragma unroll
        for (int i = 0; i < 8; i++) {
            uint4 wv = wp[i * 64];
            dot4(acc, wv, mkh(A[2*(kg16*8+i)], A[2*(kg16*8+i)+1]));
        }
        *(f32x4*)&sm.s.P16[kg16][4*cg] = acc;
    }
    __syncthreads();
    float updtmp;
    {
        float ss = 0.f;
        #pragma unroll
        for (int k = 0; k < 16; k++) ss += sm.s.P16[k][c];
        updtmp = ss * dn + bv[c];
    }
    __syncthreads();
    if (q == 0) A[c] = updtmp;
    __syncthreads();
    {
        int h = t >> 9;
        int kg = (t >> 6) & 7;
        const float* src = h ? B : A;
        const unsigned* W = h ? WhhP : WihP;
        f32x4 ar = (f32x4)0.f, az = (f32x4)0.f, an = (f32x4)0.f;
        #pragma unroll 4
        for (int i = 0; i < 16; i++) {
            int hp = kg * 16 + i;
            h16x2 av = mkh(src[2*hp], src[2*hp+1]);
            uint4 w0 = *(const uint4*)(W + hp*768 + 4*cg);
            uint4 w1 = *(const uint4*)(W + hp*768 + 256 + 4*cg);
            uint4 w2 = *(const uint4*)(W + hp*768 + 512 + 4*cg);
            dot4(ar, w0, av);
            dot4(az, w1, av);
            dot4(an, w2, av);
        }
        *(f32x4*)&sm.PG[h][kg][4*cg]       = ar;
        *(f32x4*)&sm.PG[h][kg][256 + 4*cg] = az;
        *(f32x4*)&sm.PG[h][kg][512 + 4*cg] = an;
    }
    __syncthreads();
    for (int idx = t; idx < 1536; idx += 1024) {
        int h = idx / 768, cc = idx - h * 768;
        float ss = 0.f;
        #pragma unroll
        for (int k = 0; k < 8; k++) ss += sm.PG[h][k][cc];
        G2[h][cc] = ss;
    }
    __syncthreads();
    float spc = B[c];
    float gir = bih[c]     + G2[0][c];
    float giz = bih[c+256] + G2[0][c+256];
    float gin = bih[c+512] + G2[0][c+512];
    float ghr = bhh[c]     + G2[1][c];
    float ghz = bhh[c+256] + G2[1][c+256];
    float ghn = bhh[c+512] + G2[1][c+512];
    float rg = 1.f/(1.f + __expf(-(gir+ghr)));
    float zg = 1.f/(1.f + __expf(-(giz+ghz)));
    float ng = tanhf(gin + rg*ghn);
    float hnew = (1.f - zg)*ng + zg*spc;
    float mmc = ln1024(hnew, c, lnmg, lnmb, red);
    if (q == 0) A[c] = mmc;
    __syncthreads();
    {
        int kg = t >> 7, cg1 = t & 127;
        f32x4 acc = (f32x4)0.f;
        const uint4* wp = (const uint4*)(W1P + kg * 16 * 512 + 4 * cg1);
        #pragma unroll 4
        for (int i = 0; i < 16; i++) {
            uint4 wv = wp[i * 128];
            dot4(acc, wv, mkh(A[2*(kg*16+i)], A[2*(kg*16+i)+1]));
        }
        *(f32x4*)&sm.s.H2[kg][4*cg1] = acc;
    }
    __syncthreads();
    if (t < 512) {
        float ss = b1[t];
        #pragma unroll
        for (int k = 0; k < 8; k++) ss += sm.s.H2[k][t];
        H[t] = fmaxf(ss, 0.f);
    }
    __syncthreads();
    {
        f32x4 acc = (f32x4)0.f;
        const uint4* wp = (const uint4*)(W2P + kg16 * 16 * 256 + 4 * cg);
        #pragma unroll 4
        for (int i = 0; i < 16; i++) {
            uint4 wv = wp[i * 64];
            dot4(acc, wv, mkh(H[2*(kg16*16+i)], H[2*(kg16*16+i)+1]));
        }
        *(f32x4*)&sm.s.P16[kg16][4*cg] = acc;
    }
    __syncthreads();
    float outc;
    {
        float ss = 0.f;
        #pragma unroll
        for (int k = 0; k < 16; k++) ss += sm.s.P16[k][c];
        outc = hnew + ss + b2[c];
    }
    if (t < 256) {
        slots[r*256 + c] = outc;
        if (last) outp[r*256 + c] = outc;
    }
    if (last) return;
    __syncthreads();
    float sc = ln1024(outc, c, lnsg, lnsb, red);
    if (q == 0) A[c] = sc;
    __syncthreads();
    {
        f32x4 acc = (f32x4)0.f;
        const uint4* wp = (const uint4*)(WqP + kg16 * 8 * 256 + 4 * cg);
        #pragma unroll
        for (int i = 0; i < 8; i++) {
            uint4 wv = wp[i * 64];
            dot4(acc, wv, mkh(A[2*(kg16*8+i)], A[2*(kg16*8+i)+1]));
        }
        *(f32x4*)&sm.s.P16[kg16][4*cg] = acc;
    }
    __syncthreads();
    float qc;
    {
        float ss = 0.f;
        #pragma unroll
        for (int k = 0; k < 16; k++) ss += sm.s.P16[k][c];
        qc = ss + bq[c];
    }
    {
        float v = qc * bk[c];
        #pragma unroll
        for (int m = 32; m; m >>= 1) v += __shfl_xor(v, m);
        int w = t >> 6;
        if ((t & 63) == 0) red[w][0] = v;
        __syncthreads();
        if (t == 0) {
            float S = 0.f;
            #pragma unroll
            for (int i = 0; i < 16; i++) S += red[i][0];
            qbkg[r] = SCALE_F * 0.25f * S;
        }
        __syncthreads();
    }
    if (q == 0) A[c] = qc;
    __syncthreads();
    {
        f32x4 acc = (f32x4)0.f;
        const uint4* wp = (const uint4*)(WkTP + kg16 * 8 * 256 + 4 * cg);
        #pragma unroll
        for (int i = 0; i < 8; i++) {
            uint4 wv = wp[i * 64];
            dot4(acc, wv, mkh(A[2*(kg16*8+i)], A[2*(kg16*8+i)+1]));
        }
        *(f32x4*)&sm.s.P16[kg16][4*cg] = acc;
    }
    __syncthreads();
    if (t < 256) {
        float ss = 0.f;
        #pragma unroll
        for (int k = 0; k < 16; k++) ss += sm.s.P16[k][c];
        qkg[r*256 + c] = f2bf(SCALE_F * ss);
    }
}

extern "C" void kernel_launch(void* const* d_in, const int* in_sizes, int n_in,
                              void* d_out, int out_size, void* d_ws, size_t ws_size,
                              hipStream_t stream) {
    const float* inputs = (const float*)d_in[0];
    const float* noise  = (const float*)d_in[1];
    const float* mu     = (const float*)d_in[2];
    const float* sig    = (const float*)d_in[3];
    const float* lnig   = (const float*)d_in[4];
    const float* lnib   = (const float*)d_in[5];
    const float* lnsg   = (const float*)d_in[6];
    const float* lnsb   = (const float*)d_in[7];
    const float* lnmg   = (const float*)d_in[8];
    const float* lnmb   = (const float*)d_in[9];
    const float* Wq     = (const float*)d_in[10];
    const float* bq     = (const float*)d_in[11];
    const float* Wk     = (const float*)d_in[12];
    const float* bk     = (const float*)d_in[13];
    const float* Wv     = (const float*)d_in[14];
    const float* bv     = (const float*)d_in[15];
    const float* Wih    = (const float*)d_in[16];
    const float* Whh    = (const float*)d_in[17];
    const float* bih    = (const float*)d_in[18];
    const float* bhh    = (const float*)d_in[19];
    const float* W1     = (const float*)d_in[20];
    const float* b1     = (const float*)d_in[21];
    const float* W2     = (const float*)d_in[22];
    const float* b2     = (const float*)d_in[23];

    char* ws = (char*)d_ws;
    unsigned short* lnx = (unsigned short*)ws;
    size_t off = (size_t)NB * NPOS * HIDD * 2;                                   // 64 MB
    unsigned short* qkb = (unsigned short*)(ws + off); off += (size_t)NB*NSLOT*HIDD*2;
    float* qbk   = (float*)(ws + off); off += (size_t)NB*NSLOT*4;
    float* Upart = (float*)(ws + off); off += (size_t)NB*NCHUNK*NSLOT*HIDD*4;    // 8 MB
    float* dpart = (float*)(ws + off); off += (size_t)NB*NCHUNK*NSLOT*4;
    float* slots = (float*)(ws + off); off += (size_t)NB*NSLOT*DDIM*4;
    unsigned* WqP  = (unsigned*)(ws + off); off += 32768u*4;
    unsigned* WkTP = (unsigned*)(ws + off); off += 32768u*4;
    unsigned* WvP  = (unsigned*)(ws + off); off += 32768u*4;
    unsigned* WihP = (unsigned*)(ws + off); off += 98304u*4;
    unsigned* WhhP = (unsigned*)(ws + off); off += 98304u*4;
    unsigned* W1P  = (unsigned*)(ws + off); off += 65536u*4;
    unsigned* W2P  = (unsigned*)(ws + off); off += 65536u*4;

    k_setup<<<8704, 256, 0, stream>>>(inputs, lnig, lnib, lnx,
                                      Wq, Wk, Wv, Wih, Whh, W1, W2,
                                      WqP, WkTP, WvP, WihP, WhhP, W1P, W2P,
                                      noise, mu, sig, lnsg, lnsb, bq, bk,
                                      slots, qkb, qbk);
    for (int it = 0; it < 3; it++) {
        k_stream<<<NB*NCHUNK, 128, 0, stream>>>(lnx, qkb, qbk, Upart, dpart);
        k_post<<<NB*NSLOT, 1024, 0, stream>>>(Upart, dpart,
                                              WvP, bv, WihP, WhhP, bih, bhh,
                                              lnmg, lnmb, W1P, b1, W2P, b2,
                                              lnsg, lnsb, WqP, bq, WkTP, bk,
                                              slots, qkb, qbk, (float*)d_out,
                                              it == 2 ? 1 : 0);
    }
}